// Round 1
// baseline (570.884 us; speedup 1.0000x reference)
//
#include <hip/hip_runtime.h>

#define DD 128

// ---------------- CSR build ----------------

__global__ __launch_bounds__(256) void hist_kernel(const int* __restrict__ ei,
                                                   int* __restrict__ cnt, int E) {
    int e = blockIdx.x * 256 + threadIdx.x;
    if (e < E) atomicAdd(&cnt[ei[E + e]], 1);   // dst = edge_index[1][e]
}

__global__ __launch_bounds__(256) void scan1_kernel(const int* __restrict__ cnt,
                                                    int* __restrict__ startv,
                                                    int* __restrict__ bsum, int n) {
    int i = blockIdx.x * 256 + threadIdx.x;
    int v = (i < n) ? cnt[i] : 0;
    int lane = threadIdx.x & 63, wid = threadIdx.x >> 6;
    int incl = v;
#pragma unroll
    for (int o = 1; o < 64; o <<= 1) {
        int t = __shfl_up(incl, o);
        if (lane >= o) incl += t;
    }
    __shared__ int wsum[4];
    __shared__ int wpre[4];
    if (lane == 63) wsum[wid] = incl;
    __syncthreads();
    if (threadIdx.x == 0) {
        int s = 0;
        for (int w2 = 0; w2 < 4; ++w2) { wpre[w2] = s; s += wsum[w2]; }
        bsum[blockIdx.x] = s;
    }
    __syncthreads();
    if (i < n) startv[i] = incl - v + wpre[wid];  // block-local exclusive scan
}

__global__ __launch_bounds__(512) void scan2_kernel(int* bsum, int nb) {
    int i = threadIdx.x;
    int v = (i < nb) ? bsum[i] : 0;
    int lane = threadIdx.x & 63, wid = threadIdx.x >> 6;
    int incl = v;
#pragma unroll
    for (int o = 1; o < 64; o <<= 1) {
        int t = __shfl_up(incl, o);
        if (lane >= o) incl += t;
    }
    __shared__ int wsum[8];
    __shared__ int wpre[8];
    if (lane == 63) wsum[wid] = incl;
    __syncthreads();
    if (threadIdx.x == 0) {
        int s = 0;
        for (int w2 = 0; w2 < 8; ++w2) { wpre[w2] = s; s += wsum[w2]; }
    }
    __syncthreads();
    if (i < nb) bsum[i] = incl - v + wpre[wid];   // exclusive block offsets
}

__global__ __launch_bounds__(256) void scan3_kernel(int* startv, int* cursor,
                                                    const int* __restrict__ bsum,
                                                    int n, int E) {
    int i = blockIdx.x * 256 + threadIdx.x;
    if (i < n) {
        int s = startv[i] + bsum[i >> 8];
        startv[i] = s;
        cursor[i] = s;
    } else if (i == n) {
        startv[n] = E;
    }
}

__global__ __launch_bounds__(256) void fill_kernel(const int* __restrict__ ei,
                                                   const int* __restrict__ ety,
                                                   const float* __restrict__ ew,
                                                   int* cursor,
                                                   int* __restrict__ csrs,
                                                   int* __restrict__ csrt,
                                                   float* __restrict__ csrw, int E) {
    int e = blockIdx.x * 256 + threadIdx.x;
    if (e >= E) return;
    int dst = ei[E + e];
    int p = atomicAdd(&cursor[dst], 1);
    csrs[p] = ei[e];       // src
    csrt[p] = ety[e];      // relation
    csrw[p] = ew[e];       // weight
}

// ---------------- aggregation (segment_sum of (x[src]-rel[t])*w) ----------------

__global__ __launch_bounds__(256) void aggregate_kernel(
    const float* __restrict__ x, const float* __restrict__ rel,
    const int* __restrict__ startv, const int* __restrict__ csrs,
    const int* __restrict__ csrt, const float* __restrict__ csrw,
    float* __restrict__ agg, int n) {
    int gid = blockIdx.x * 256 + threadIdx.x;
    int node = gid >> 5;
    int c = gid & 31;              // float4 chunk within the 128-wide row
    if (node >= n) return;
    int s = startv[node], epos = startv[node + 1];
    float4 acc = make_float4(0.f, 0.f, 0.f, 0.f);
    for (int idx = s; idx < epos; ++idx) {
        int src = csrs[idx];
        int t = csrt[idx];
        float w = csrw[idx];
        float4 xs = ((const float4*)x)[(size_t)src * 32 + c];
        float4 rv = ((const float4*)rel)[(size_t)t * 32 + c];
        acc.x += (xs.x - rv.x) * w;
        acc.y += (xs.y - rv.y) * w;
        acc.z += (xs.z - rv.z) * w;
        acc.w += (xs.w - rv.w) * w;
    }
    ((float4*)agg)[(size_t)node * 32 + c] = acc;
}

// ---------------- 128x128 GEMM pass: out[row] = (addsrc?addsrc[row]:0) + A[row]@W ----------------
// A/out/addsrc may alias (row-wise in-place is safe: each lane reads its full row
// before storing). W is staged f32 in 64 KB LDS.

__global__ __launch_bounds__(256) void gemm128_kernel(const float* A,
                                                      const float* __restrict__ W,
                                                      const float* addsrc,
                                                      float* out, int nrows, int relu) {
    __shared__ float sW[DD * DD];
    {
        float4* d = (float4*)sW;
        const float4* s = (const float4*)W;
        for (int i = threadIdx.x; i < DD * DD / 4; i += 256) d[i] = s[i];
    }
    __syncthreads();
    int j4 = (threadIdx.x & 31) << 2;   // output column start (4 cols per lane)
    int rslot = threadIdx.x >> 5;       // 8 rows in flight per block pass
    int base = blockIdx.x * 32;
    for (int r0 = 0; r0 < 32; r0 += 8) {
        int row = base + r0 + rslot;
        if (row < nrows) {
            const float4* A4 = (const float4*)(A + (size_t)row * DD);
            float4 acc = make_float4(0.f, 0.f, 0.f, 0.f);
#pragma unroll
            for (int k4 = 0; k4 < 32; ++k4) {
                float4 av = A4[k4];
                const float* wp = sW + (k4 * 4) * DD + j4;
                float4 w0 = *(const float4*)(wp);
                float4 w1 = *(const float4*)(wp + DD);
                float4 w2 = *(const float4*)(wp + 2 * DD);
                float4 w3 = *(const float4*)(wp + 3 * DD);
                acc.x += av.x * w0.x + av.y * w1.x + av.z * w2.x + av.w * w3.x;
                acc.y += av.x * w0.y + av.y * w1.y + av.z * w2.y + av.w * w3.y;
                acc.z += av.x * w0.z + av.y * w1.z + av.z * w2.z + av.w * w3.z;
                acc.w += av.x * w0.w + av.y * w1.w + av.z * w2.w + av.w * w3.w;
            }
            if (addsrc) {
                float4 ad = *(const float4*)(addsrc + (size_t)row * DD + j4);
                acc.x += ad.x; acc.y += ad.y; acc.z += ad.z; acc.w += ad.w;
            }
            if (relu) {
                acc.x = fmaxf(acc.x, 0.f); acc.y = fmaxf(acc.y, 0.f);
                acc.z = fmaxf(acc.z, 0.f); acc.w = fmaxf(acc.w, 0.f);
            }
            *(float4*)(out + (size_t)row * DD + j4) = acc;
        }
    }
}

// ---------------- launcher ----------------

extern "C" void kernel_launch(void* const* d_in, const int* in_sizes, int n_in,
                              void* d_out, int out_size, void* d_ws, size_t ws_size,
                              hipStream_t stream) {
    const int*   ei  = (const int*)d_in[0];
    const int*   ety = (const int*)d_in[1];
    const float* ew  = (const float*)d_in[2];
    const float* x0  = (const float*)d_in[3];
    const float* r0  = (const float*)d_in[4];
    const float* W0  = (const float*)d_in[5];
    const float* Ws0 = (const float*)d_in[6];
    const float* Wr0 = (const float*)d_in[7];
    const float* W1  = (const float*)d_in[8];
    const float* Ws1 = (const float*)d_in[9];
    const float* Wr1 = (const float*)d_in[10];

    const int E = in_sizes[1];
    const int N = in_sizes[3] / DD;
    const int R = in_sizes[4] / DD;

    float* out_x = (float*)d_out;                 // [N,128]
    float* out_r = out_x + (size_t)N * DD;        // [R,128]

    char* w = (char*)d_ws;
    size_t off = 0;
    auto alloc = [&](size_t bytes) {
        void* p = w + off;
        off += (bytes + 255) & ~(size_t)255;
        return p;
    };
    float* agg    = (float*)alloc((size_t)N * DD * 4);   // 51.2 MB
    float* rel1   = (float*)alloc((size_t)R * DD * 4);
    int*   startv = (int*)alloc((size_t)(N + 1) * 4);
    int*   cursor = (int*)alloc((size_t)N * 4);
    int*   bsum   = (int*)alloc(512 * 4);
    int*   csrs   = (int*)alloc((size_t)E * 4);
    int*   csrt   = (int*)alloc((size_t)E * 4);
    float* csrw   = (float*)alloc((size_t)E * 4);
    (void)ws_size; (void)n_in; (void)out_size;

    // --- build CSR (reused by both layers) ---
    int* cnt = cursor;  // cnt's lifetime ends before cursor is written
    hipMemsetAsync(cnt, 0, (size_t)N * 4, stream);
    int ebl = (E + 255) / 256;
    int nb  = (N + 255) / 256;
    hist_kernel<<<ebl, 256, 0, stream>>>(ei, cnt, E);
    scan1_kernel<<<nb, 256, 0, stream>>>(cnt, startv, bsum, N);
    scan2_kernel<<<1, 512, 0, stream>>>(bsum, nb);
    scan3_kernel<<<(N + 1 + 255) / 256, 256, 0, stream>>>(startv, cursor, bsum, N, E);
    fill_kernel<<<ebl, 256, 0, stream>>>(ei, ety, ew, cursor, csrs, csrt, csrw, E);

    int abl = (int)(((size_t)N * 32 + 255) / 256);
    int gbl = (N + 31) / 32;
    int rbl = (R + 31) / 32;

    // --- layer 0 ---
    aggregate_kernel<<<abl, 256, 0, stream>>>(x0, r0, startv, csrs, csrt, csrw, agg, N);
    gemm128_kernel<<<gbl, 256, 0, stream>>>(agg, W0, nullptr, agg, N, 0);     // agg = agg@W0
    gemm128_kernel<<<gbl, 256, 0, stream>>>(x0, Ws0, agg, out_x, N, 1);       // x1 = relu(x0@Wself0 + agg)
    gemm128_kernel<<<rbl, 256, 0, stream>>>(r0, Wr0, nullptr, rel1, R, 1);    // rel1 = relu(rel0@Wrel0)

    // --- layer 1 ---
    aggregate_kernel<<<abl, 256, 0, stream>>>(out_x, rel1, startv, csrs, csrt, csrw, agg, N);
    gemm128_kernel<<<gbl, 256, 0, stream>>>(agg, W1, nullptr, agg, N, 0);     // agg = agg@W1
    gemm128_kernel<<<gbl, 256, 0, stream>>>(out_x, Ws1, agg, out_x, N, 0);    // x2 = x1@Wself1 + agg
    gemm128_kernel<<<rbl, 256, 0, stream>>>(rel1, Wr1, nullptr, out_r, R, 0); // rel2 = rel1@Wrel1
}

// Round 2
// 277.980 us; speedup vs baseline: 2.0537x; 2.0537x over previous
//
#include <hip/hip_runtime.h>

#define DD 128

typedef __attribute__((ext_vector_type(8))) short bf16x8;
typedef __attribute__((ext_vector_type(4))) float f32x4;

__device__ __forceinline__ float b2f(unsigned short u) {
    return __uint_as_float(((unsigned)u) << 16);
}
__device__ __forceinline__ unsigned short f2b(float f) {
    unsigned u = __float_as_uint(f);
    unsigned r = (u + 0x7FFFu + ((u >> 16) & 1u)) >> 16;
    return (unsigned short)r;
}

// ---------------- CSR build ----------------

__global__ __launch_bounds__(256) void hist_kernel(const int* __restrict__ ei,
                                                   int* __restrict__ cnt, int E) {
    int e = blockIdx.x * 256 + threadIdx.x;
    if (e < E) atomicAdd(&cnt[ei[E + e]], 1);   // dst = edge_index[1][e]
}

__global__ __launch_bounds__(256) void scan1_kernel(const int* __restrict__ cnt,
                                                    int* __restrict__ startv,
                                                    int* __restrict__ bsum, int n) {
    int i = blockIdx.x * 256 + threadIdx.x;
    int v = (i < n) ? cnt[i] : 0;
    int lane = threadIdx.x & 63, wid = threadIdx.x >> 6;
    int incl = v;
#pragma unroll
    for (int o = 1; o < 64; o <<= 1) {
        int t = __shfl_up(incl, o);
        if (lane >= o) incl += t;
    }
    __shared__ int wsum[4];
    __shared__ int wpre[4];
    if (lane == 63) wsum[wid] = incl;
    __syncthreads();
    if (threadIdx.x == 0) {
        int s = 0;
        for (int w2 = 0; w2 < 4; ++w2) { wpre[w2] = s; s += wsum[w2]; }
        bsum[blockIdx.x] = s;
    }
    __syncthreads();
    if (i < n) startv[i] = incl - v + wpre[wid];
}

__global__ __launch_bounds__(512) void scan2_kernel(int* bsum, int nb) {
    int i = threadIdx.x;
    int v = (i < nb) ? bsum[i] : 0;
    int lane = threadIdx.x & 63, wid = threadIdx.x >> 6;
    int incl = v;
#pragma unroll
    for (int o = 1; o < 64; o <<= 1) {
        int t = __shfl_up(incl, o);
        if (lane >= o) incl += t;
    }
    __shared__ int wsum[8];
    __shared__ int wpre[8];
    if (lane == 63) wsum[wid] = incl;
    __syncthreads();
    if (threadIdx.x == 0) {
        int s = 0;
        for (int w2 = 0; w2 < 8; ++w2) { wpre[w2] = s; s += wsum[w2]; }
    }
    __syncthreads();
    if (i < nb) bsum[i] = incl - v + wpre[wid];
}

__global__ __launch_bounds__(256) void scan3_kernel(int* startv, int* cursor,
                                                    const int* __restrict__ bsum,
                                                    int n, int E) {
    int i = blockIdx.x * 256 + threadIdx.x;
    if (i < n) {
        int s = startv[i] + bsum[i >> 8];
        startv[i] = s;
        cursor[i] = s;
    } else if (i == n) {
        startv[n] = E;
    }
}

__global__ __launch_bounds__(256) void fill_kernel(const int* __restrict__ ei,
                                                   const int* __restrict__ ety,
                                                   const float* __restrict__ ew,
                                                   int* cursor,
                                                   unsigned* __restrict__ csrp,
                                                   float* __restrict__ csrw, int E) {
    int e = blockIdx.x * 256 + threadIdx.x;
    if (e >= E) return;
    int dst = ei[E + e];
    int p = atomicAdd(&cursor[dst], 1);
    csrp[p] = ((unsigned)ei[e]) | (((unsigned)ety[e]) << 20);  // src | (rel<<20)
    csrw[p] = ew[e];
}

// ---------------- conversions ----------------

__global__ __launch_bounds__(256) void cvt_f32_bf16_kernel(const float* __restrict__ in,
                                                           unsigned short* __restrict__ out,
                                                           int n4) {
    int i = blockIdx.x * 256 + threadIdx.x;
    if (i < n4) {
        float4 v = ((const float4*)in)[i];
        ushort4 o = make_ushort4(f2b(v.x), f2b(v.y), f2b(v.z), f2b(v.w));
        ((ushort4*)out)[i] = o;
    }
}

// Wt[c*128+k] = bf16(W[k*128+c])  (transpose + convert, 128x128)
__global__ __launch_bounds__(256) void build_wt_kernel(const float* __restrict__ W,
                                                       unsigned short* __restrict__ Wt) {
    int i = blockIdx.x * 256 + threadIdx.x;   // 0..16383
    int c = i >> 7, k = i & 127;
    Wt[i] = f2b(W[k * DD + c]);
}

// ---------------- aggregation: aggb[n] = bf16( sum_e w*(x[src]-rel[t]) ) ----------------

__global__ __launch_bounds__(256) void aggregate_kernel(
    const unsigned short* __restrict__ xb, const float* __restrict__ rel,
    const int* __restrict__ startv, const unsigned* __restrict__ csrp,
    const float* __restrict__ csrw, unsigned short* __restrict__ aggb, int n) {
    int gid = blockIdx.x * 256 + threadIdx.x;
    int node = gid >> 5;
    int c = gid & 31;              // ushort4 / float4 chunk within the 128-wide row
    if (node >= n) return;
    int s = startv[node], e = startv[node + 1];
    float ax = 0.f, ay = 0.f, az = 0.f, aw = 0.f;
    for (int i = s; i < e; ++i) {
        unsigned p = csrp[i];
        int src = (int)(p & 0xFFFFFu);
        int t = (int)(p >> 20);
        float w = csrw[i];
        ushort4 xs = ((const ushort4*)xb)[(size_t)src * 32 + c];
        float4 rv = ((const float4*)rel)[(size_t)t * 32 + c];
        ax += (b2f(xs.x) - rv.x) * w;
        ay += (b2f(xs.y) - rv.y) * w;
        az += (b2f(xs.z) - rv.z) * w;
        aw += (b2f(xs.w) - rv.w) * w;
    }
    ushort4 o = make_ushort4(f2b(ax), f2b(ay), f2b(az), f2b(aw));
    ((ushort4*)aggb)[(size_t)node * 32 + c] = o;
}

// ---------------- fused dual GEMM via MFMA ----------------
// out = A@W + X@Wself  (A,X bf16 row-major [nrows,128]; WtA/WtX bf16 transposed [col][k])
// outb: bf16 out (layer0), outf: f32 out (layer1). relu applied before store.

__global__ __launch_bounds__(256) void mfma_dual_gemm_kernel(
    const unsigned short* __restrict__ A, const unsigned short* __restrict__ X,
    const unsigned short* __restrict__ WtA, const unsigned short* __restrict__ WtX,
    float* __restrict__ outf, unsigned short* __restrict__ outb,
    int nrows, int relu) {
    __shared__ unsigned short sW[2][DD * DD];
    {
        const unsigned short* src0 = WtA;
        const unsigned short* src1 = WtX;
        for (int i = threadIdx.x; i < 2048; i += 256) {
            int row = i >> 4, slot = i & 15;
            int so = (slot ^ (row & 15)) * 8;
            *(float4*)&sW[0][row * DD + so] = ((const float4*)src0)[i];
            *(float4*)&sW[1][row * DD + so] = ((const float4*)src1)[i];
        }
    }
    __syncthreads();
    int w = threadIdx.x >> 6, l = threadIdx.x & 63;
    int lr = l & 15, lk = l >> 4;         // A-frag row / k-group; C-frag col / row-group
    int brow = blockIdx.x * 128 + w * 32;
    int r0 = brow + lr, r1 = brow + 16 + lr;
    bool v0 = r0 < nrows, v1 = r1 < nrows;

    f32x4 acc[2][8];
#pragma unroll
    for (int rt = 0; rt < 2; ++rt)
#pragma unroll
        for (int ct = 0; ct < 8; ++ct) acc[rt][ct] = (f32x4){0.f, 0.f, 0.f, 0.f};

#pragma unroll
    for (int kb = 0; kb < 4; ++kb) {
        int koff = kb * 32 + lk * 8;
        bf16x8 a0 = {}, a1 = {}, x0 = {}, x1 = {};
        if (v0) {
            a0 = *(const bf16x8*)(A + (size_t)r0 * DD + koff);
            x0 = *(const bf16x8*)(X + (size_t)r0 * DD + koff);
        }
        if (v1) {
            a1 = *(const bf16x8*)(A + (size_t)r1 * DD + koff);
            x1 = *(const bf16x8*)(X + (size_t)r1 * DD + koff);
        }
#pragma unroll
        for (int ct = 0; ct < 8; ++ct) {
            int wrow = ct * 16 + lr;
            int slot = kb * 4 + lk;
            int so = (slot ^ (wrow & 15)) * 8;
            bf16x8 bw = *(const bf16x8*)&sW[0][wrow * DD + so];
            bf16x8 bs = *(const bf16x8*)&sW[1][wrow * DD + so];
            acc[0][ct] = __builtin_amdgcn_mfma_f32_16x16x32_bf16(a0, bw, acc[0][ct], 0, 0, 0);
            acc[0][ct] = __builtin_amdgcn_mfma_f32_16x16x32_bf16(x0, bs, acc[0][ct], 0, 0, 0);
            acc[1][ct] = __builtin_amdgcn_mfma_f32_16x16x32_bf16(a1, bw, acc[1][ct], 0, 0, 0);
            acc[1][ct] = __builtin_amdgcn_mfma_f32_16x16x32_bf16(x1, bs, acc[1][ct], 0, 0, 0);
        }
    }

    // epilogue: C/D layout: col = l&15, row = (l>>4)*4 + reg
#pragma unroll
    for (int rt = 0; rt < 2; ++rt) {
        int rowbase = brow + rt * 16 + lk * 4;
#pragma unroll
        for (int ct = 0; ct < 8; ++ct) {
            int c = ct * 16 + lr;
            f32x4 v = acc[rt][ct];
            if (relu) {
                v[0] = fmaxf(v[0], 0.f); v[1] = fmaxf(v[1], 0.f);
                v[2] = fmaxf(v[2], 0.f); v[3] = fmaxf(v[3], 0.f);
            }
#pragma unroll
            for (int j = 0; j < 4; ++j) {
                int rr = rowbase + j;
                if (rr < nrows) {
                    if (outb) outb[(size_t)rr * DD + c] = f2b(v[j]);
                    if (outf) outf[(size_t)rr * DD + c] = v[j];
                }
            }
        }
    }
}

// ---------------- small f32 GEMM (rel path, 200 rows) ----------------

__global__ __launch_bounds__(256) void gemm128_kernel(const float* A,
                                                      const float* __restrict__ W,
                                                      float* out, int nrows, int relu) {
    __shared__ float sW[DD * DD];
    {
        float4* d = (float4*)sW;
        const float4* s = (const float4*)W;
        for (int i = threadIdx.x; i < DD * DD / 4; i += 256) d[i] = s[i];
    }
    __syncthreads();
    int j4 = (threadIdx.x & 31) << 2;
    int rslot = threadIdx.x >> 5;
    int base = blockIdx.x * 32;
    for (int r0 = 0; r0 < 32; r0 += 8) {
        int row = base + r0 + rslot;
        if (row < nrows) {
            const float4* A4 = (const float4*)(A + (size_t)row * DD);
            float4 acc = make_float4(0.f, 0.f, 0.f, 0.f);
#pragma unroll
            for (int k4 = 0; k4 < 32; ++k4) {
                float4 av = A4[k4];
                const float* wp = sW + (k4 * 4) * DD + j4;
                float4 w0 = *(const float4*)(wp);
                float4 w1 = *(const float4*)(wp + DD);
                float4 w2 = *(const float4*)(wp + 2 * DD);
                float4 w3 = *(const float4*)(wp + 3 * DD);
                acc.x += av.x * w0.x + av.y * w1.x + av.z * w2.x + av.w * w3.x;
                acc.y += av.x * w0.y + av.y * w1.y + av.z * w2.y + av.w * w3.y;
                acc.z += av.x * w0.z + av.y * w1.z + av.z * w2.z + av.w * w3.z;
                acc.w += av.x * w0.w + av.y * w1.w + av.z * w2.w + av.w * w3.w;
            }
            if (relu) {
                acc.x = fmaxf(acc.x, 0.f); acc.y = fmaxf(acc.y, 0.f);
                acc.z = fmaxf(acc.z, 0.f); acc.w = fmaxf(acc.w, 0.f);
            }
            *(float4*)(out + (size_t)row * DD + j4) = acc;
        }
    }
}

// ---------------- launcher ----------------

extern "C" void kernel_launch(void* const* d_in, const int* in_sizes, int n_in,
                              void* d_out, int out_size, void* d_ws, size_t ws_size,
                              hipStream_t stream) {
    const int*   ei  = (const int*)d_in[0];
    const int*   ety = (const int*)d_in[1];
    const float* ew  = (const float*)d_in[2];
    const float* x0  = (const float*)d_in[3];
    const float* r0  = (const float*)d_in[4];
    const float* W0  = (const float*)d_in[5];
    const float* Ws0 = (const float*)d_in[6];
    const float* Wr0 = (const float*)d_in[7];
    const float* W1  = (const float*)d_in[8];
    const float* Ws1 = (const float*)d_in[9];
    const float* Wr1 = (const float*)d_in[10];

    const int E = in_sizes[1];
    const int N = in_sizes[3] / DD;
    const int R = in_sizes[4] / DD;

    float* out_x = (float*)d_out;                 // [N,128] f32
    float* out_r = out_x + (size_t)N * DD;        // [R,128] f32

    char* w = (char*)d_ws;
    size_t off = 0;
    auto alloc = [&](size_t bytes) {
        void* p = w + off;
        off += (bytes + 255) & ~(size_t)255;
        return p;
    };
    unsigned short* aggb = (unsigned short*)alloc((size_t)N * DD * 2);  // 25.6 MB
    unsigned short* xb   = (unsigned short*)alloc((size_t)N * DD * 2);  // 25.6 MB (x0b, then x1b in place)
    unsigned short* wt0a = (unsigned short*)alloc((size_t)DD * DD * 2);
    unsigned short* wt0s = (unsigned short*)alloc((size_t)DD * DD * 2);
    unsigned short* wt1a = (unsigned short*)alloc((size_t)DD * DD * 2);
    unsigned short* wt1s = (unsigned short*)alloc((size_t)DD * DD * 2);
    float* rel1   = (float*)alloc((size_t)R * DD * 4);
    int*   startv = (int*)alloc((size_t)(N + 1) * 4);
    int*   cursor = (int*)alloc((size_t)N * 4);
    int*   bsum   = (int*)alloc(512 * 4);
    unsigned* csrp = (unsigned*)alloc((size_t)E * 4);
    float*    csrw = (float*)alloc((size_t)E * 4);
    (void)ws_size; (void)n_in; (void)out_size;

    // --- build CSR (reused by both layers) ---
    int* cnt = cursor;
    hipMemsetAsync(cnt, 0, (size_t)N * 4, stream);
    int ebl = (E + 255) / 256;
    int nb  = (N + 255) / 256;
    hist_kernel<<<ebl, 256, 0, stream>>>(ei, cnt, E);
    scan1_kernel<<<nb, 256, 0, stream>>>(cnt, startv, bsum, N);
    scan2_kernel<<<1, 512, 0, stream>>>(bsum, nb);
    scan3_kernel<<<(N + 1 + 255) / 256, 256, 0, stream>>>(startv, cursor, bsum, N, E);
    fill_kernel<<<ebl, 256, 0, stream>>>(ei, ety, ew, cursor, csrp, csrw, E);

    // --- conversions ---
    int n4 = N * 32;
    cvt_f32_bf16_kernel<<<(n4 + 255) / 256, 256, 0, stream>>>(x0, xb, n4);
    build_wt_kernel<<<64, 256, 0, stream>>>(W0, wt0a);
    build_wt_kernel<<<64, 256, 0, stream>>>(Ws0, wt0s);
    build_wt_kernel<<<64, 256, 0, stream>>>(W1, wt1a);
    build_wt_kernel<<<64, 256, 0, stream>>>(Ws1, wt1s);

    int abl = (int)(((size_t)N * 32 + 255) / 256);
    int gbl = (N + 127) / 128;
    int rbl = (R + 31) / 32;

    // --- layer 0 ---
    aggregate_kernel<<<abl, 256, 0, stream>>>(xb, r0, startv, csrp, csrw, aggb, N);
    // x1b = relu(aggb@W0 + x0b@Wself0), bf16 in place of xb (row-wise in-place safe)
    mfma_dual_gemm_kernel<<<gbl, 256, 0, stream>>>(aggb, xb, wt0a, wt0s,
                                                   nullptr, xb, N, 1);
    gemm128_kernel<<<rbl, 256, 0, stream>>>(r0, Wr0, rel1, R, 1);   // rel1 = relu(r0@Wrel0)

    // --- layer 1 ---
    aggregate_kernel<<<abl, 256, 0, stream>>>(xb, rel1, startv, csrp, csrw, aggb, N);
    mfma_dual_gemm_kernel<<<gbl, 256, 0, stream>>>(aggb, xb, wt1a, wt1s,
                                                   out_x, nullptr, N, 0);
    gemm128_kernel<<<rbl, 256, 0, stream>>>(rel1, Wr1, out_r, R, 0); // rel2 = rel1@Wrel1
}

// Round 3
// 233.715 us; speedup vs baseline: 2.4427x; 1.1894x over previous
//
#include <hip/hip_runtime.h>

#define DD 128

typedef __attribute__((ext_vector_type(8))) short bf16x8;
typedef __attribute__((ext_vector_type(4))) float f32x4;

__device__ __forceinline__ float b2f(unsigned short u) {
    return __uint_as_float(((unsigned)u) << 16);
}
__device__ __forceinline__ unsigned short f2b(float f) {
    unsigned u = __float_as_uint(f);
    unsigned r = (u + 0x7FFFu + ((u >> 16) & 1u)) >> 16;
    return (unsigned short)r;
}

// ---------------- CSR build ----------------

__global__ __launch_bounds__(256) void hist_kernel(const int* __restrict__ ei,
                                                   int* __restrict__ cnt, int E) {
    int e = blockIdx.x * 256 + threadIdx.x;
    if (e < E) atomicAdd(&cnt[ei[E + e]], 1);   // dst = edge_index[1][e]
}

__global__ __launch_bounds__(256) void scan1_kernel(const int* __restrict__ cnt,
                                                    int* __restrict__ startv,
                                                    int* __restrict__ bsum, int n) {
    int i = blockIdx.x * 256 + threadIdx.x;
    int v = (i < n) ? cnt[i] : 0;
    int lane = threadIdx.x & 63, wid = threadIdx.x >> 6;
    int incl = v;
#pragma unroll
    for (int o = 1; o < 64; o <<= 1) {
        int t = __shfl_up(incl, o);
        if (lane >= o) incl += t;
    }
    __shared__ int wsum[4];
    __shared__ int wpre[4];
    if (lane == 63) wsum[wid] = incl;
    __syncthreads();
    if (threadIdx.x == 0) {
        int s = 0;
        for (int w2 = 0; w2 < 4; ++w2) { wpre[w2] = s; s += wsum[w2]; }
        bsum[blockIdx.x] = s;
    }
    __syncthreads();
    if (i < n) startv[i] = incl - v + wpre[wid];
}

__global__ __launch_bounds__(512) void scan2_kernel(int* bsum, int nb) {
    int i = threadIdx.x;
    int v = (i < nb) ? bsum[i] : 0;
    int lane = threadIdx.x & 63, wid = threadIdx.x >> 6;
    int incl = v;
#pragma unroll
    for (int o = 1; o < 64; o <<= 1) {
        int t = __shfl_up(incl, o);
        if (lane >= o) incl += t;
    }
    __shared__ int wsum[8];
    __shared__ int wpre[8];
    if (lane == 63) wsum[wid] = incl;
    __syncthreads();
    if (threadIdx.x == 0) {
        int s = 0;
        for (int w2 = 0; w2 < 8; ++w2) { wpre[w2] = s; s += wsum[w2]; }
    }
    __syncthreads();
    if (i < nb) bsum[i] = incl - v + wpre[wid];
}

__global__ __launch_bounds__(256) void scan3_kernel(int* startv, int* cursor,
                                                    const int* __restrict__ bsum,
                                                    int n, int E) {
    int i = blockIdx.x * 256 + threadIdx.x;
    if (i < n) {
        int s = startv[i] + bsum[i >> 8];
        startv[i] = s;
        cursor[i] = s;
    } else if (i == n) {
        startv[n] = E;
    }
}

__global__ __launch_bounds__(256) void fill_kernel(const int* __restrict__ ei,
                                                   const int* __restrict__ ety,
                                                   const float* __restrict__ ew,
                                                   int* cursor,
                                                   uint2* __restrict__ csre, int E) {
    int e = blockIdx.x * 256 + threadIdx.x;
    if (e >= E) return;
    int dst = ei[E + e];
    int p = atomicAdd(&cursor[dst], 1);
    uint2 rec;
    rec.x = ((unsigned)ei[e]) | (((unsigned)ety[e]) << 20);  // src | (rel<<20)
    rec.y = __float_as_uint(ew[e]);
    csre[p] = rec;
}

// ---------------- merged conversions ----------------
// blocks [0,bx): x0->xb ; [bx,bx+br): r0->r0b ; [bx+br, bx+br+256): 4 W transposes

__global__ __launch_bounds__(256) void prep_kernel(
    const float* __restrict__ x0, unsigned short* __restrict__ xb, int bx, int n4x,
    const float* __restrict__ r0, unsigned short* __restrict__ r0b, int br, int n4r,
    const float* __restrict__ W0, const float* __restrict__ Ws0,
    const float* __restrict__ W1, const float* __restrict__ Ws1,
    unsigned short* __restrict__ wt0a, unsigned short* __restrict__ wt0s,
    unsigned short* __restrict__ wt1a, unsigned short* __restrict__ wt1s) {
    int bid = blockIdx.x;
    if (bid < bx) {
        int i = bid * 256 + threadIdx.x;
        if (i < n4x) {
            float4 v = ((const float4*)x0)[i];
            ((ushort4*)xb)[i] = make_ushort4(f2b(v.x), f2b(v.y), f2b(v.z), f2b(v.w));
        }
    } else if (bid < bx + br) {
        int i = (bid - bx) * 256 + threadIdx.x;
        if (i < n4r) {
            float4 v = ((const float4*)r0)[i];
            ((ushort4*)r0b)[i] = make_ushort4(f2b(v.x), f2b(v.y), f2b(v.z), f2b(v.w));
        }
    } else {
        int t = bid - bx - br;                 // 0..255
        int which = t >> 6;                    // 0..3
        int i = (t & 63) * 256 + threadIdx.x;  // 0..16383
        int cc = i >> 7, k = i & 127;
        const float* Wsel = which == 0 ? W0 : which == 1 ? Ws0 : which == 2 ? W1 : Ws1;
        unsigned short* Osel = which == 0 ? wt0a : which == 1 ? wt0s : which == 2 ? wt1a : wt1s;
        Osel[i] = f2b(Wsel[k * DD + cc]);      // Wt[c][k] = W[k][c]
    }
}

// ---------------- aggregation: aggb[n] = bf16( sum_e w*(x[src]-rel[t]) ) ----------------
// 16 lanes per node (ushort8 chunk each), 2-deep edge unroll -> 8 gather chains/wave.

__global__ __launch_bounds__(256) void aggregate_kernel(
    const unsigned short* __restrict__ xb, const unsigned short* __restrict__ relb,
    const int* __restrict__ startv, const uint2* __restrict__ csre,
    unsigned short* __restrict__ aggb, int n) {
    int gid = blockIdx.x * 256 + threadIdx.x;
    int node = gid >> 4;
    int c = gid & 15;                 // 16B chunk within the 256B bf16 row
    if (node >= n) return;
    int s = startv[node], e = startv[node + 1];
    const bf16x8* X = (const bf16x8*)xb;
    const bf16x8* Rl = (const bf16x8*)relb;
    float a0[8], a1[8];
#pragma unroll
    for (int j = 0; j < 8; ++j) { a0[j] = 0.f; a1[j] = 0.f; }
    int i = s;
    for (; i + 2 <= e; i += 2) {
        uint2 p0 = csre[i];
        uint2 p1 = csre[i + 1];
        bf16x8 xv0 = X[(size_t)(p0.x & 0xFFFFFu) * 16 + c];
        bf16x8 rv0 = Rl[(p0.x >> 20) * 16 + c];
        bf16x8 xv1 = X[(size_t)(p1.x & 0xFFFFFu) * 16 + c];
        bf16x8 rv1 = Rl[(p1.x >> 20) * 16 + c];
        float w0 = __uint_as_float(p0.y), w1 = __uint_as_float(p1.y);
#pragma unroll
        for (int j = 0; j < 8; ++j) {
            a0[j] += (b2f((unsigned short)xv0[j]) - b2f((unsigned short)rv0[j])) * w0;
            a1[j] += (b2f((unsigned short)xv1[j]) - b2f((unsigned short)rv1[j])) * w1;
        }
    }
    if (i < e) {
        uint2 p0 = csre[i];
        bf16x8 xv0 = X[(size_t)(p0.x & 0xFFFFFu) * 16 + c];
        bf16x8 rv0 = Rl[(p0.x >> 20) * 16 + c];
        float w0 = __uint_as_float(p0.y);
#pragma unroll
        for (int j = 0; j < 8; ++j)
            a0[j] += (b2f((unsigned short)xv0[j]) - b2f((unsigned short)rv0[j])) * w0;
    }
    bf16x8 ov;
#pragma unroll
    for (int j = 0; j < 8; ++j) ov[j] = (short)f2b(a0[j] + a1[j]);
    ((bf16x8*)aggb)[(size_t)node * 16 + c] = ov;
}

// ---------------- fused dual GEMM via MFMA (swapped operands -> vectorized stores) ----
// out = A@W + X@Wself. mfma(Wfrag, Afrag) yields C^T layout: lane (lr=l&15, lk=l>>4)
// holds C[brow + rt*16 + lr][ct*16 + lk*4 + reg] -> one f32x4/bf16x4 store per tile.

__global__ __launch_bounds__(256) void mfma_dual_gemm_kernel(
    const unsigned short* __restrict__ A, const unsigned short* __restrict__ X,
    const unsigned short* __restrict__ WtA, const unsigned short* __restrict__ WtX,
    float* __restrict__ outf, unsigned short* __restrict__ outb,
    int nrows, int relu) {
    __shared__ unsigned short sW[2][DD * DD];
    for (int i = threadIdx.x; i < 2048; i += 256) {
        int row = i >> 4, slot = i & 15;
        int so = (slot ^ (row & 15)) * 8;
        *(float4*)&sW[0][row * DD + so] = ((const float4*)WtA)[i];
        *(float4*)&sW[1][row * DD + so] = ((const float4*)WtX)[i];
    }
    __syncthreads();
    int w = threadIdx.x >> 6, l = threadIdx.x & 63;
    int lr = l & 15, lk = l >> 4;
    int brow = blockIdx.x * 128 + w * 32;
    int r0 = brow + lr, r1 = brow + 16 + lr;
    bool v0 = r0 < nrows, v1 = r1 < nrows;

    f32x4 acc[2][8];
#pragma unroll
    for (int rt = 0; rt < 2; ++rt)
#pragma unroll
        for (int ct = 0; ct < 8; ++ct) acc[rt][ct] = (f32x4){0.f, 0.f, 0.f, 0.f};

#pragma unroll
    for (int kb = 0; kb < 4; ++kb) {
        int koff = kb * 32 + lk * 8;
        bf16x8 a0 = {}, a1 = {}, x0 = {}, x1 = {};
        if (v0) {
            a0 = *(const bf16x8*)(A + (size_t)r0 * DD + koff);
            x0 = *(const bf16x8*)(X + (size_t)r0 * DD + koff);
        }
        if (v1) {
            a1 = *(const bf16x8*)(A + (size_t)r1 * DD + koff);
            x1 = *(const bf16x8*)(X + (size_t)r1 * DD + koff);
        }
#pragma unroll
        for (int ct = 0; ct < 8; ++ct) {
            int wrow = ct * 16 + lr;
            int slot = kb * 4 + lk;
            int so = (slot ^ (wrow & 15)) * 8;
            bf16x8 bw = *(const bf16x8*)&sW[0][wrow * DD + so];
            bf16x8 bs = *(const bf16x8*)&sW[1][wrow * DD + so];
            acc[0][ct] = __builtin_amdgcn_mfma_f32_16x16x32_bf16(bw, a0, acc[0][ct], 0, 0, 0);
            acc[0][ct] = __builtin_amdgcn_mfma_f32_16x16x32_bf16(bs, x0, acc[0][ct], 0, 0, 0);
            acc[1][ct] = __builtin_amdgcn_mfma_f32_16x16x32_bf16(bw, a1, acc[1][ct], 0, 0, 0);
            acc[1][ct] = __builtin_amdgcn_mfma_f32_16x16x32_bf16(bs, x1, acc[1][ct], 0, 0, 0);
        }
    }

#pragma unroll
    for (int rt = 0; rt < 2; ++rt) {
        int row = brow + rt * 16 + lr;
        if (row < nrows) {
#pragma unroll
            for (int ct = 0; ct < 8; ++ct) {
                f32x4 v = acc[rt][ct];
                if (relu) {
                    v[0] = fmaxf(v[0], 0.f); v[1] = fmaxf(v[1], 0.f);
                    v[2] = fmaxf(v[2], 0.f); v[3] = fmaxf(v[3], 0.f);
                }
                int cb = ct * 16 + lk * 4;
                if (outf) *(f32x4*)(outf + (size_t)row * DD + cb) = v;
                if (outb) {
                    ushort4 o = make_ushort4(f2b(v[0]), f2b(v[1]), f2b(v[2]), f2b(v[3]));
                    *(ushort4*)(outb + (size_t)row * DD + cb) = o;
                }
            }
        }
    }
}

// ---------------- small f32 GEMM (rel path, 200 rows), optional bf16 copy ----------------

__global__ __launch_bounds__(256) void gemm128_kernel(const float* A,
                                                      const float* __restrict__ W,
                                                      float* out, unsigned short* outb,
                                                      int nrows, int relu) {
    __shared__ float sW[DD * DD];
    {
        float4* d = (float4*)sW;
        const float4* s = (const float4*)W;
        for (int i = threadIdx.x; i < DD * DD / 4; i += 256) d[i] = s[i];
    }
    __syncthreads();
    int j4 = (threadIdx.x & 31) << 2;
    int rslot = threadIdx.x >> 5;
    int base = blockIdx.x * 32;
    for (int r0 = 0; r0 < 32; r0 += 8) {
        int row = base + r0 + rslot;
        if (row < nrows) {
            const float4* A4 = (const float4*)(A + (size_t)row * DD);
            float4 acc = make_float4(0.f, 0.f, 0.f, 0.f);
#pragma unroll
            for (int k4 = 0; k4 < 32; ++k4) {
                float4 av = A4[k4];
                const float* wp = sW + (k4 * 4) * DD + j4;
                float4 w0 = *(const float4*)(wp);
                float4 w1 = *(const float4*)(wp + DD);
                float4 w2 = *(const float4*)(wp + 2 * DD);
                float4 w3 = *(const float4*)(wp + 3 * DD);
                acc.x += av.x * w0.x + av.y * w1.x + av.z * w2.x + av.w * w3.x;
                acc.y += av.x * w0.y + av.y * w1.y + av.z * w2.y + av.w * w3.y;
                acc.z += av.x * w0.z + av.y * w1.z + av.z * w2.z + av.w * w3.z;
                acc.w += av.x * w0.w + av.y * w1.w + av.z * w2.w + av.w * w3.w;
            }
            if (relu) {
                acc.x = fmaxf(acc.x, 0.f); acc.y = fmaxf(acc.y, 0.f);
                acc.z = fmaxf(acc.z, 0.f); acc.w = fmaxf(acc.w, 0.f);
            }
            if (out) *(float4*)(out + (size_t)row * DD + j4) = acc;
            if (outb) {
                ushort4 o = make_ushort4(f2b(acc.x), f2b(acc.y), f2b(acc.z), f2b(acc.w));
                *(ushort4*)(outb + (size_t)row * DD + j4) = o;
            }
        }
    }
}

// ---------------- launcher ----------------

extern "C" void kernel_launch(void* const* d_in, const int* in_sizes, int n_in,
                              void* d_out, int out_size, void* d_ws, size_t ws_size,
                              hipStream_t stream) {
    const int*   ei  = (const int*)d_in[0];
    const int*   ety = (const int*)d_in[1];
    const float* ew  = (const float*)d_in[2];
    const float* x0  = (const float*)d_in[3];
    const float* r0  = (const float*)d_in[4];
    const float* W0  = (const float*)d_in[5];
    const float* Ws0 = (const float*)d_in[6];
    const float* Wr0 = (const float*)d_in[7];
    const float* W1  = (const float*)d_in[8];
    const float* Ws1 = (const float*)d_in[9];
    const float* Wr1 = (const float*)d_in[10];

    const int E = in_sizes[1];
    const int N = in_sizes[3] / DD;
    const int R = in_sizes[4] / DD;

    float* out_x = (float*)d_out;                 // [N,128] f32
    float* out_r = out_x + (size_t)N * DD;        // [R,128] f32

    char* w = (char*)d_ws;
    size_t off = 0;
    auto alloc = [&](size_t bytes) {
        void* p = w + off;
        off += (bytes + 255) & ~(size_t)255;
        return p;
    };
    unsigned short* aggb  = (unsigned short*)alloc((size_t)N * DD * 2);  // 25.6 MB
    unsigned short* xb    = (unsigned short*)alloc((size_t)N * DD * 2);  // 25.6 MB
    unsigned short* r0b   = (unsigned short*)alloc((size_t)R * DD * 2);
    unsigned short* rel1b = (unsigned short*)alloc((size_t)R * DD * 2);
    unsigned short* wt0a  = (unsigned short*)alloc((size_t)DD * DD * 2);
    unsigned short* wt0s  = (unsigned short*)alloc((size_t)DD * DD * 2);
    unsigned short* wt1a  = (unsigned short*)alloc((size_t)DD * DD * 2);
    unsigned short* wt1s  = (unsigned short*)alloc((size_t)DD * DD * 2);
    float* rel1   = (float*)alloc((size_t)R * DD * 4);
    int*   startv = (int*)alloc((size_t)(N + 1) * 4);
    int*   cursor = (int*)alloc((size_t)N * 4);
    int*   bsum   = (int*)alloc(512 * 4);
    uint2* csre   = (uint2*)alloc((size_t)E * 8);
    (void)ws_size; (void)n_in; (void)out_size;

    // --- build CSR (reused by both layers) ---
    int* cnt = cursor;
    hipMemsetAsync(cnt, 0, (size_t)N * 4, stream);
    int ebl = (E + 255) / 256;
    int nb  = (N + 255) / 256;
    hist_kernel<<<ebl, 256, 0, stream>>>(ei, cnt, E);
    scan1_kernel<<<nb, 256, 0, stream>>>(cnt, startv, bsum, N);
    scan2_kernel<<<1, 512, 0, stream>>>(bsum, nb);
    scan3_kernel<<<(N + 1 + 255) / 256, 256, 0, stream>>>(startv, cursor, bsum, N, E);
    fill_kernel<<<ebl, 256, 0, stream>>>(ei, ety, ew, cursor, csre, E);

    // --- conversions (merged) ---
    int n4x = N * 32, n4r = R * 32;
    int bx = (n4x + 255) / 256, br = (n4r + 255) / 256;
    prep_kernel<<<bx + br + 256, 256, 0, stream>>>(x0, xb, bx, n4x, r0, r0b, br, n4r,
                                                   W0, Ws0, W1, Ws1,
                                                   wt0a, wt0s, wt1a, wt1s);

    int abl = (int)(((size_t)N * 16 + 255) / 256);
    int gbl = (N + 127) / 128;
    int rbl = (R + 31) / 32;

    // --- layer 0 ---
    aggregate_kernel<<<abl, 256, 0, stream>>>(xb, r0b, startv, csre, aggb, N);
    mfma_dual_gemm_kernel<<<gbl, 256, 0, stream>>>(aggb, xb, wt0a, wt0s,
                                                   nullptr, xb, N, 1);
    gemm128_kernel<<<rbl, 256, 0, stream>>>(r0, Wr0, rel1, rel1b, R, 1);

    // --- layer 1 ---
    aggregate_kernel<<<abl, 256, 0, stream>>>(xb, rel1b, startv, csre, aggb, N);
    mfma_dual_gemm_kernel<<<gbl, 256, 0, stream>>>(aggb, xb, wt1a, wt1s,
                                                   out_x, nullptr, N, 0);
    gemm128_kernel<<<rbl, 256, 0, stream>>>(rel1, Wr1, out_r, nullptr, R, 0);
}